// Round 7
// baseline (24134.602 us; speedup 1.0000x reference)
//
#include <hip/hip_runtime.h>

// ModularSSMWorldModel: persistent 16-block kernel, one module per block.
// Round 10: EXCHANGE DECOUPLING (software-pipelined overlap consumption).
//   R6 calibration: 2^22 dependent FMA chain hidden inside 15.4ms -> clock
//   >= 1.1 GHz; R4: 240 CUs of MFMA load doesn't move dur. Downclock dead.
//   Compute per step < 1k cy vs >= 17k measured -> step is exchange/visibility
//   stalls. Neighbor data feeds ONLY stage1 ks16/ks19 (2 of 20 MFMAs).
//   Restructure: stage1 partA (ks0..15,17,18) -> poll step t-1 strips
//   (issued BEFORE partA, checked after via vmcnt(8); x prefetch issued
//   after poll loads so the counted wait skips it) -> overlap EMA (t-1)
//   -> partB (ks16,19) -> stage2 -> push(t) -> interior EMA (t).
//   V (push->visible) now hides under a full compute phase instead of
//   being paid serially every step. 2 slots still suffice: poll precedes
//   push within a step, so a slot can't be overwritten before its read.
// Exchange: {seq,value} u64 self-validating pairs, double-buffered by t&1.

typedef _Float16 f16;
typedef __attribute__((ext_vector_type(8)))  _Float16 f16x8;
typedef __attribute__((ext_vector_type(16))) float    f32x16;
typedef __attribute__((ext_vector_type(4)))  float    f32x4;
typedef __attribute__((ext_vector_type(4)))  float    float4v;
typedef unsigned long long u64;

#define OUT_STATES 33554432ull            // 32*1024*1024
#define EXCH_U64S  (16ull * 2 * 2 * 512)  // [bound][dir][slot][32*16]
#define EXCH_OFF   256                    // control region before exchange
#define WS_BYTES   (EXCH_OFF + EXCH_U64S * 8)

// dynamic LDS carve
#define AF_OFF  0         // f16 Afrag[35*64*8]            35840 B
#define HS_OFF  35840     // f16 Hs[32*136]                 8704 B
#define UP_OFF  44544     // float updS[32*308]            39424 B
#define DEC_OFF 83968     // float decL[304]                1216 B
#define EXL_OFF 85184     // float exL[512]                 2048 B
#define LDS_TOT 87232

#define SPIN_CAP (1 << 21)   // hang-proof: give up after ~2M retries, latch

struct Ptrs {
  const float *x, *W1, *b1, *W2, *b2, *W1L, *b1L, *W2L, *b2L, *draw;
  float* out;
  int* ctl;            // ctl[0] = done flag for clock-keeper blocks
  u64* exch;
};

__device__ __forceinline__ float sigm(float v) { return 1.0f / (1.0f + __expf(-v)); }

// lgkm-only barrier: LDS producer/consumer sync without draining VMEM.
__device__ __forceinline__ void bar_lds() {
  asm volatile("s_waitcnt lgkmcnt(0)\n\ts_barrier" ::: "memory");
}

__device__ __forceinline__ u64* exslot(u64* e, int bound, int dir, int slot) {
  return e + (size_t)(((bound * 2 + dir) * 2 + slot) * 512);
}

// producer push: agent-scope relaxed store (R1/R4 semantics — measured correct)
__device__ __forceinline__ void push_ex(u64* p, unsigned seq, float val) {
  u64 v = ((u64)seq << 32) | (u64)__float_as_uint(val);
  __hip_atomic_store(p, v, __ATOMIC_RELAXED, __HIP_MEMORY_SCOPE_AGENT);
}

// issue 8 strip loads from ONE base + imm offsets (b stride 4*16 u64 = 512B)
__device__ __forceinline__ void iss8(const u64* b,
    u64& g0, u64& g1, u64& g2, u64& g3, u64& g4, u64& g5, u64& g6, u64& g7) {
  asm volatile(
      "global_load_dwordx2 %0, %8, off sc0 sc1\n\t"
      "global_load_dwordx2 %1, %8, off offset:512 sc0 sc1\n\t"
      "global_load_dwordx2 %2, %8, off offset:1024 sc0 sc1\n\t"
      "global_load_dwordx2 %3, %8, off offset:1536 sc0 sc1\n\t"
      "global_load_dwordx2 %4, %8, off offset:2048 sc0 sc1\n\t"
      "global_load_dwordx2 %5, %8, off offset:2560 sc0 sc1\n\t"
      "global_load_dwordx2 %6, %8, off offset:3072 sc0 sc1\n\t"
      "global_load_dwordx2 %7, %8, off offset:3584 sc0 sc1"
      : "=&v"(g0), "=&v"(g1), "=&v"(g2), "=&v"(g3),
        "=&v"(g4), "=&v"(g5), "=&v"(g6), "=&v"(g7)
      : "v"(b) : "memory");
}
__device__ __forceinline__ void iss2(const u64* b, u64& g0, u64& g1) {
  asm volatile(
      "global_load_dwordx2 %0, %2, off sc0 sc1\n\t"
      "global_load_dwordx2 %1, %2, off offset:2048 sc0 sc1"
      : "=&v"(g0), "=&v"(g1) : "v"(b) : "memory");
}
// counted / full waits; "+v" on the poll regs pins the check AFTER the wait
// (rule #18: register-only ops can hoist past a bare asm waitcnt).
__device__ __forceinline__ void vmw8(u64& g0, u64& g1, u64& g2, u64& g3,
                                     u64& g4, u64& g5, u64& g6, u64& g7) {
  asm volatile("s_waitcnt vmcnt(8)"
      : "+v"(g0), "+v"(g1), "+v"(g2), "+v"(g3),
        "+v"(g4), "+v"(g5), "+v"(g6), "+v"(g7) :: "memory");
}
__device__ __forceinline__ void vmw0(u64& g0, u64& g1, u64& g2, u64& g3,
                                     u64& g4, u64& g5, u64& g6, u64& g7) {
  asm volatile("s_waitcnt vmcnt(0)"
      : "+v"(g0), "+v"(g1), "+v"(g2), "+v"(g3),
        "+v"(g4), "+v"(g5), "+v"(g6), "+v"(g7) :: "memory");
}
__device__ __forceinline__ void vmw8_2(u64& g0, u64& g1) {
  asm volatile("s_waitcnt vmcnt(8)" : "+v"(g0), "+v"(g1) :: "memory");
}
__device__ __forceinline__ void vmw0_2(u64& g0, u64& g1) {
  asm volatile("s_waitcnt vmcnt(0)" : "+v"(g0), "+v"(g1) :: "memory");
}

template<bool LAST>
__device__ void run_block(const int m, const Ptrs P) {
  constexpr int KS1 = LAST ? 35 : 20;   // stage1 K-steps of 16 (K = 560 / 320)
  constexpr int U   = LAST ? 5  : 1;    // stage2 n-tiles per wave
  constexpr int NT  = LAST ? 19 : 4;    // stage2 total 16-wide n-tiles
  constexpr int SW  = LAST ? 304: 64;   // state slice width
  constexpr int NU  = LAST ? 38 : 8;    // update items per thread (32*SW/256)
  constexpr int UPW = LAST ? 308: 68;   // updS leading-dim pad

  const int tid = threadIdx.x;
  const int L = tid & 63;
  const int w = tid >> 6;               // wave id 0..3
  const int p0 = 48 * m;                // slice start (48*15 == 720)

  extern __shared__ __align__(16) char smem[];
  f16*   Afrag = (f16*)(smem + AF_OFF);
  f16*   Hs    = (f16*)(smem + HS_OFF);
  float* updS  = (float*)(smem + UP_OFF);
  float* decL  = (float*)(smem + DEC_OFF);
  float* exL   = (float*)(smem + EXL_OFF);

  int dead = 0;                          // sticky poll give-up latch

  // ---- load weights into registers as MFMA B-fragments (persist all steps) ----
  f16x8 w1f[KS1];
  #pragma unroll
  for (int ks = 0; ks < KS1; ++ks) {
    #pragma unroll
    for (int e = 0; e < 8; ++e) {
      int c = 16 * ks + 8 * (L >> 5) + e;          // K index
      int h = 32 * w + (L & 31);                   // N index
      float wv = LAST ? P.W1L[(size_t)c * 128 + h]
                      : P.W1[((size_t)m * 320 + c) * 128 + h];
      w1f[ks][e] = (f16)wv;
    }
  }
  f16x8 w2f[U][4];
  float b2v[U];
  #pragma unroll
  for (int u = 0; u < U; ++u) {
    int nt = w + 4 * u;
    if (nt < NT) {
      int s = 16 * nt + (L & 15);
      #pragma unroll
      for (int ks = 0; ks < 4; ++ks)
        #pragma unroll
        for (int e = 0; e < 8; ++e) {
          int k = 32 * ks + 8 * ((L >> 4) & 3) + e;
          float wv = LAST ? P.W2L[(size_t)k * 304 + s]
                          : P.W2[((size_t)m * 128 + k) * 64 + s];
          w2f[u][ks][e] = (f16)wv;
        }
      b2v[u] = LAST ? P.b2L[s] : P.b2[m * 64 + s];
    }
  }
  const float b1v = LAST ? P.b1L[32 * w + (L & 31)] : P.b1[m * 128 + 32 * w + (L & 31)];

  for (int sl = tid; sl < SW; sl += 256) decL[sl] = sigm(P.draw[p0 + sl]);

  // zero A-frag (state cols must start at 0)
  for (int ch = tid; ch < 35 * 64; ch += 256) {
    f16x8 z;
    #pragma unroll
    for (int e = 0; e < 8; ++e) z[e] = (f16)0.0f;
    *(f16x8*)&Afrag[ch * 8] = z;
  }
  float sreg[NU];
  #pragma unroll
  for (int u = 0; u < NU; ++u) sreg[u] = 0.0f;

  // deferred-poll identity and bases (non-last: per-thread strip role)
  const int sl_ = tid & 63;
  const int b0_ = tid >> 6;
  int side = -1;
  u64 *pbs0 = nullptr, *pbs1 = nullptr;   // poll bases for slot 0 / slot 1
  if (!LAST) {
    side = (sl_ < 16 && m > 0) ? 0 : (sl_ >= 48 ? 1 : -1);
    if (side == 0) {
      pbs0 = exslot(P.exch, m - 1, 0, 0) + sl_ + b0_ * 16;
      pbs1 = exslot(P.exch, m - 1, 0, 1) + sl_ + b0_ * 16;
    } else if (side == 1) {
      pbs0 = exslot(P.exch, m, 1, 0) + (sl_ - 48) + b0_ * 16;
      pbs1 = exslot(P.exch, m, 1, 1) + (sl_ - 48) + b0_ * 16;
    }
  } else {
    pbs0 = exslot(P.exch, 14, 0, 0) + tid;
    pbs1 = exslot(P.exch, 14, 0, 1) + tid;
  }
  u64 g0, g1, g2, g3, g4, g5, g6, g7;

  // x prefetch registers: thread covers (b = tid>>3, cols xc0..xc0+31)
  const int xb = tid >> 3, xc0 = (tid & 7) * 32;
  float4v xr[8];
  {
    const float* xp = P.x + ((size_t)xb * 1024 + 0) * 256 + xc0;
    #pragma unroll
    for (int i = 0; i < 8; ++i) xr[i] = *(const float4v*)(xp + 4 * i);
  }
  __syncthreads();

  for (int t = 0; t < 1024; ++t) {
    const int slot = t & 1;
    const unsigned seq  = (unsigned)(t + 1);
    const int pslot = (t + 1) & 1;        // == (t-1)&1 : slot of step t-1 data
    const unsigned pseq = (unsigned)t;    // seq of step t-1 data

    // ---- (a) stage x_t into A-frag chunks (from prefetched regs) ----
    #pragma unroll
    for (int i = 0; i < 4; ++i) {
      int c = xc0 + 8 * i;
      int ks = c >> 4, h8 = (c >> 3) & 1;
      int chunk = (ks * 64 + xb + 32 * h8) ^ (ks & 7);
      f16x8 av;
      #pragma unroll
      for (int e = 0; e < 4; ++e) {
        av[e]     = (f16)xr[2 * i][e];
        av[4 + e] = (f16)xr[2 * i + 1][e];
      }
      *(f16x8*)&Afrag[chunk * 8] = av;
    }
    bar_lds();                            // (b)

    // ---- (b') issue poll loads FIRST (oldest), then x prefetch (younger) ----
    if (t > 0) {
      if (!LAST) {
        if (side >= 0) iss8(pslot ? pbs1 : pbs0, g0, g1, g2, g3, g4, g5, g6, g7);
      } else {
        iss2(pslot ? pbs1 : pbs0, g0, g1);
      }
    }
    {
      int tn = (t + 1 < 1024) ? (t + 1) : 1023;
      const float* xp = P.x + ((size_t)xb * 1024 + tn) * 256 + xc0;
      #pragma unroll
      for (int i = 0; i < 8; ++i) xr[i] = *(const float4v*)(xp + 4 * i);
    }

    // ---- (c) stage1 partA: neighbor-independent K-steps ----
    f32x16 acc;
    #pragma unroll
    for (int r = 0; r < 16; ++r) acc[r] = b1v;
    #pragma unroll
    for (int ks = 0; ks < KS1; ++ks) {
      if (ks == 16 || (!LAST && ks == 19)) continue;   // deferred overlap cols
      int chunk = (ks * 64 + L) ^ (ks & 7);
      f16x8 a = *(const f16x8*)&Afrag[chunk * 8];
      acc = __builtin_amdgcn_mfma_f32_32x32x16_f16(a, w1f[ks], acc, 0, 0, 0);
    }

    // ---- (d)+(e) wait/retry poll, overlap EMA for step t-1 ----
    if (t > 0) {
      if (!LAST) {
        if (side >= 0) {
          vmw8(g0, g1, g2, g3, g4, g5, g6, g7);   // poll loads done; x still fly
          for (int spin = 0;; ++spin) {
            bool ok = ((unsigned)(g0 >> 32) == pseq) && ((unsigned)(g1 >> 32) == pseq)
                   && ((unsigned)(g2 >> 32) == pseq) && ((unsigned)(g3 >> 32) == pseq)
                   && ((unsigned)(g4 >> 32) == pseq) && ((unsigned)(g5 >> 32) == pseq)
                   && ((unsigned)(g6 >> 32) == pseq) && ((unsigned)(g7 >> 32) == pseq);
            if (ok) break;
            if (dead | (spin > SPIN_CAP)) { dead = 1; break; }
            asm volatile("s_sleep 2" ::: "memory");
            iss8(pslot ? pbs1 : pbs0, g0, g1, g2, g3, g4, g5, g6, g7);
            vmw0(g0, g1, g2, g3, g4, g5, g6, g7);
          }
          u64 got[8] = {g0, g1, g2, g3, g4, g5, g6, g7};
          const float d = decL[sl_];
          #pragma unroll
          for (int u = 0; u < 8; ++u) {
            int b = b0_ + 4 * u;
            float val = (updS[b * UPW + sl_]
                       + __uint_as_float((unsigned)(got[u] & 0xffffffffull))) * 0.5f;
            float sn = d * sreg[u] + (1.0f - d) * val;
            sreg[u] = sn;
            int c = 256 + sl_;
            int ks = c >> 4, h8 = (c >> 3) & 1, e = c & 7;
            int chunk = (ks * 64 + b + 32 * h8) ^ (ks & 7);
            Afrag[chunk * 8 + e] = (f16)sn;
            if (sl_ < 48)
              P.out[(size_t)b * 1048576 + (size_t)(t - 1) * 1024 + p0 + sl_] = sn;
          }
        }
      } else {
        vmw8_2(g0, g1);
        for (int spin = 0;; ++spin) {
          bool ok = ((unsigned)(g0 >> 32) == pseq) && ((unsigned)(g1 >> 32) == pseq);
          if (ok) break;
          if (dead | (spin > SPIN_CAP)) { dead = 1; break; }
          asm volatile("s_sleep 2" ::: "memory");
          iss2(pslot ? pbs1 : pbs0, g0, g1);
          vmw0_2(g0, g1);
        }
        exL[tid]       = __uint_as_float((unsigned)(g0 & 0xffffffffull));
        exL[tid + 256] = __uint_as_float((unsigned)(g1 & 0xffffffffull));
        bar_lds();
        #pragma unroll
        for (int u = 0; u < NU; ++u) {
          const int q  = (256 * u) / 304;
          const int r2 = 256 * u - q * 304;
          int slx = tid + r2;
          int b  = q + (slx >= 304 ? 1 : 0);
          int sl = slx - (slx >= 304 ? 304 : 0);
          if (sl < 16) {
            float val = (updS[b * UPW + sl] + exL[b * 16 + sl]) * 0.5f;
            float d = decL[sl];
            float sn = d * sreg[u] + (1.0f - d) * val;
            sreg[u] = sn;
            int c = 256 + sl;
            int ks = c >> 4, h8 = (c >> 3) & 1, e = c & 7;
            int chunk = (ks * 64 + b + 32 * h8) ^ (ks & 7);
            Afrag[chunk * 8 + e] = (f16)sn;
            P.out[(size_t)b * 1048576 + (size_t)(t - 1) * 1024 + 720 + sl] = sn;
          }
        }
      }
    }
    bar_lds();                            // (f): overlap Afrag -> partB readers

    // ---- (g) stage1 partB: deferred overlap K-steps + silu epilogue ----
    {
      int chunk16 = (16 * 64 + L) ^ (16 & 7);
      f16x8 a16 = *(const f16x8*)&Afrag[chunk16 * 8];
      acc = __builtin_amdgcn_mfma_f32_32x32x16_f16(a16, w1f[16], acc, 0, 0, 0);
      if (!LAST) {
        int chunk19 = (19 * 64 + L) ^ (19 & 7);
        f16x8 a19 = *(const f16x8*)&Afrag[chunk19 * 8];
        acc = __builtin_amdgcn_mfma_f32_32x32x16_f16(a19, w1f[19], acc, 0, 0, 0);
      }
    }
    {
      int j = 32 * w + (L & 31);
      #pragma unroll
      for (int r = 0; r < 16; ++r) {
        int row = 4 * (L >> 5) + (r & 3) + 8 * (r >> 2);
        float v = acc[r];
        Hs[row * 136 + j] = (f16)(v * sigm(v));
      }
    }
    bar_lds();                            // (h)

    // ---- (i) stage2: upd = H @ W2 + b2 ----
    f32x4 acc2[U][2];
    #pragma unroll
    for (int u = 0; u < U; ++u) {
      int nt = w + 4 * u;
      if (nt < NT) {
        #pragma unroll
        for (int mt = 0; mt < 2; ++mt)
          #pragma unroll
          for (int r = 0; r < 4; ++r) acc2[u][mt][r] = b2v[u];
      }
    }
    #pragma unroll
    for (int mt = 0; mt < 2; ++mt) {
      #pragma unroll
      for (int ks = 0; ks < 4; ++ks) {
        int hb = (L & 15) + 16 * mt;
        int kb = 32 * ks + 8 * ((L >> 4) & 3);
        f16x8 a = *(const f16x8*)&Hs[hb * 136 + kb];
        #pragma unroll
        for (int u = 0; u < U; ++u) {
          int nt = w + 4 * u;
          if (nt < NT)
            acc2[u][mt] = __builtin_amdgcn_mfma_f32_16x16x32_f16(a, w2f[u][ks], acc2[u][mt], 0, 0, 0);
        }
      }
    }

    // own updates -> LDS; overlap strips -> exchange (push seq=t+1, slot=t&1)
    #pragma unroll
    for (int u = 0; u < U; ++u) {
      int nt = w + 4 * u;
      if (nt < NT) {
        int s = 16 * nt + (L & 15);
        #pragma unroll
        for (int mt = 0; mt < 2; ++mt)
          #pragma unroll
          for (int r = 0; r < 4; ++r) {
            int b = 16 * mt + 4 * (L >> 4) + r;
            updS[b * UPW + s] = acc2[u][mt][r];
          }
      }
    }
    if (!LAST) {
      if (w == 0 && m > 0) {
        u64* base = exslot(P.exch, m - 1, 1, slot) + (L & 15);
        #pragma unroll
        for (int mt = 0; mt < 2; ++mt)
          #pragma unroll
          for (int r = 0; r < 4; ++r) {
            int b = 16 * mt + 4 * (L >> 4) + r;
            push_ex(base + b * 16, seq, acc2[0][mt][r]);
          }
      }
      if (w == 3) {
        u64* base = exslot(P.exch, m, 0, slot) + (L & 15);
        #pragma unroll
        for (int mt = 0; mt < 2; ++mt)
          #pragma unroll
          for (int r = 0; r < 4; ++r) {
            int b = 16 * mt + 4 * (L >> 4) + r;
            push_ex(base + b * 16, seq, acc2[0][mt][r]);
          }
      }
    } else {
      if (w == 0) {
        u64* base = exslot(P.exch, 14, 1, slot) + (L & 15);
        #pragma unroll
        for (int mt = 0; mt < 2; ++mt)
          #pragma unroll
          for (int r = 0; r < 4; ++r) {
            int b = 16 * mt + 4 * (L >> 4) + r;
            push_ex(base + b * 16, seq, acc2[0][mt][r]);
          }
      }
    }
    bar_lds();                            // (j): updS -> interior EMA readers

    // ---- (k) interior EMA for step t (no neighbor needed) ----
    if (!LAST) {
      if (side < 0) {
        const float d = decL[sl_];
        #pragma unroll
        for (int u = 0; u < 8; ++u) {
          int b = b0_ + 4 * u;
          float val = updS[b * UPW + sl_];
          float sn = d * sreg[u] + (1.0f - d) * val;
          sreg[u] = sn;
          int c = 256 + sl_;
          int ks = c >> 4, h8 = (c >> 3) & 1, e = c & 7;
          int chunk = (ks * 64 + b + 32 * h8) ^ (ks & 7);
          Afrag[chunk * 8 + e] = (f16)sn;
          if (sl_ < 48) {
            P.out[(size_t)b * 1048576 + (size_t)t * 1024 + p0 + sl_] = sn;
            if (t == 1023)
              P.out[OUT_STATES + (size_t)b * 1024 + p0 + sl_] = sn;
          }
        }
      }
    } else {
      #pragma unroll
      for (int u = 0; u < NU; ++u) {
        const int q  = (256 * u) / 304;
        const int r2 = 256 * u - q * 304;
        int slx = tid + r2;
        int b  = q + (slx >= 304 ? 1 : 0);
        int sl = slx - (slx >= 304 ? 304 : 0);
        if (sl >= 16) {
          float val = updS[b * UPW + sl];
          float d = decL[sl];
          float sn = d * sreg[u] + (1.0f - d) * val;
          sreg[u] = sn;
          int c = 256 + sl;
          int ks = c >> 4, h8 = (c >> 3) & 1, e = c & 7;
          int chunk = (ks * 64 + b + 32 * h8) ^ (ks & 7);
          Afrag[chunk * 8 + e] = (f16)sn;
          P.out[(size_t)b * 1048576 + (size_t)t * 1024 + 720 + sl] = sn;
          if (t == 1023)
            P.out[OUT_STATES + (size_t)b * 1024 + 720 + sl] = sn;
        }
      }
    }
    // loop-top bar (b) orders (k)/(a) writes before next partA reads
  }

  // ---- epilogue: consume step-1023 overlap (seq 1024, slot 1) ----
  if (!LAST) {
    if (side >= 0) {
      iss8(pbs1, g0, g1, g2, g3, g4, g5, g6, g7);
      vmw0(g0, g1, g2, g3, g4, g5, g6, g7);
      for (int spin = 0;; ++spin) {
        bool ok = ((unsigned)(g0 >> 32) == 1024u) && ((unsigned)(g1 >> 32) == 1024u)
               && ((unsigned)(g2 >> 32) == 1024u) && ((unsigned)(g3 >> 32) == 1024u)
               && ((unsigned)(g4 >> 32) == 1024u) && ((unsigned)(g5 >> 32) == 1024u)
               && ((unsigned)(g6 >> 32) == 1024u) && ((unsigned)(g7 >> 32) == 1024u);
        if (ok) break;
        if (dead | (spin > SPIN_CAP)) { dead = 1; break; }
        asm volatile("s_sleep 2" ::: "memory");
        iss8(pbs1, g0, g1, g2, g3, g4, g5, g6, g7);
        vmw0(g0, g1, g2, g3, g4, g5, g6, g7);
      }
      u64 got[8] = {g0, g1, g2, g3, g4, g5, g6, g7};
      const float d = decL[sl_];
      #pragma unroll
      for (int u = 0; u < 8; ++u) {
        int b = b0_ + 4 * u;
        float val = (updS[b * UPW + sl_]
                   + __uint_as_float((unsigned)(got[u] & 0xffffffffull))) * 0.5f;
        float sn = d * sreg[u] + (1.0f - d) * val;
        sreg[u] = sn;
        if (sl_ < 48) {
          P.out[(size_t)b * 1048576 + 1023ull * 1024 + p0 + sl_] = sn;
          P.out[OUT_STATES + (size_t)b * 1024 + p0 + sl_] = sn;
        }
      }
    }
  } else {
    iss2(pbs1, g0, g1);
    vmw0_2(g0, g1);
    for (int spin = 0;; ++spin) {
      bool ok = ((unsigned)(g0 >> 32) == 1024u) && ((unsigned)(g1 >> 32) == 1024u);
      if (ok) break;
      if (dead | (spin > SPIN_CAP)) { dead = 1; break; }
      asm volatile("s_sleep 2" ::: "memory");
      iss2(pbs1, g0, g1);
      vmw0_2(g0, g1);
    }
    exL[tid]       = __uint_as_float((unsigned)(g0 & 0xffffffffull));
    exL[tid + 256] = __uint_as_float((unsigned)(g1 & 0xffffffffull));
    bar_lds();
    #pragma unroll
    for (int u = 0; u < NU; ++u) {
      const int q  = (256 * u) / 304;
      const int r2 = 256 * u - q * 304;
      int slx = tid + r2;
      int b  = q + (slx >= 304 ? 1 : 0);
      int sl = slx - (slx >= 304 ? 304 : 0);
      if (sl < 16) {
        float val = (updS[b * UPW + sl] + exL[b * 16 + sl]) * 0.5f;
        float d = decL[sl];
        float sn = d * sreg[u] + (1.0f - d) * val;
        sreg[u] = sn;
        P.out[(size_t)b * 1048576 + 1023ull * 1024 + 720 + sl] = sn;
        P.out[OUT_STATES + (size_t)b * 1024 + 720 + sl] = sn;
      }
    }
  }

  // signal clock-keepers to exit (m15 is the straggler)
  if (LAST && tid == 0)
    __hip_atomic_store(P.ctl, 1, __ATOMIC_RELAXED, __HIP_MEMORY_SCOPE_AGENT);
}

// Dependent-MFMA spin keeper (R4, measured active: MfmaUtil 13.9%).
__device__ void clock_keeper(const Ptrs P) {
  f16x8 z;
  #pragma unroll
  for (int e = 0; e < 8; ++e) z[e] = (f16)((threadIdx.x & 1) ? 0.0f : 1e-6f);
  f32x4 acc = {0.0f, 0.0f, 0.0f, 0.0f};
  for (;;) {
    #pragma unroll 16
    for (int i = 0; i < 1024; ++i)
      acc = __builtin_amdgcn_mfma_f32_16x16x32_f16(z, z, acc, 0, 0, 0);
    if (__hip_atomic_load(P.ctl, __ATOMIC_RELAXED, __HIP_MEMORY_SCOPE_AGENT) != 0)
      break;
  }
  if (acc[0] == 123.456f)
    ((volatile float*)P.out)[0] = acc[0];
}

__global__ __launch_bounds__(256, 1) void ssm_kernel(Ptrs P) {
  const int blk = blockIdx.x;
  if (blk >= 16) { clock_keeper(P); return; }
  if (blk == 15) run_block<true>(15, P);
  else           run_block<false>(blk, P);
}

extern "C" void kernel_launch(void* const* d_in, const int* in_sizes, int n_in,
                              void* d_out, int out_size, void* d_ws, size_t ws_size,
                              hipStream_t stream) {
  (void)in_sizes; (void)n_in; (void)out_size; (void)ws_size;
  Ptrs P;
  P.x    = (const float*)d_in[0];
  P.W1   = (const float*)d_in[1];
  P.b1   = (const float*)d_in[2];
  P.W2   = (const float*)d_in[3];
  P.b2   = (const float*)d_in[4];
  P.W1L  = (const float*)d_in[5];
  P.b1L  = (const float*)d_in[6];
  P.W2L  = (const float*)d_in[7];
  P.b2L  = (const float*)d_in[8];
  P.draw = (const float*)d_in[9];
  P.out  = (float*)d_out;
  P.ctl  = (int*)d_ws;
  P.exch = (u64*)((char*)d_ws + EXCH_OFF);

  hipMemsetAsync(d_ws, 0, WS_BYTES, stream);
  hipLaunchKernelGGL(ssm_kernel, dim3(256), dim3(256), LDS_TOT, stream, P);
}

// Round 8
// 9917.369 us; speedup vs baseline: 2.4336x; 2.4336x over previous
//
#include <hip/hip_runtime.h>

// ModularSSMWorldModel: persistent 16-block kernel, one module per block.
// Round 11: R4 flow (measured 15.45ms) + M15 DE-SPILL. No flow changes.
//   R10 post-mortem: deferred-poll pipeline +57% with FETCH/WRITE flat and
//   VGPR pinned at 256 -> regression was register pressure, not polls.
//   m15 (LAST) carries ~295 persistent VGPRs in R4 (w1f 140, w2f 80, xr 32,
//   sreg 38) -> chronic scratch spills; scratch is L2-resident (no HBM
//   signature) but its reload latency feeds m15's serial chains; ring rate
//   = slowest block = m15. Fix (LAST path only):
//     1. w1f ks20..34 -> LDS fragments (-60 VGPR, LDS 87->145KB, 1 blk/CU)
//     2. no persistent x prefetch for m15 (-32): direct row-t loads in (a)
//     3. stage2 per-u accumulation (acc2 40 -> 8 live)
//   Non-LAST path byte-identical to R4. Calib spinner removed (would mask
//   a win if clock ~1.1GHz). Keepers: R4 MFMA spin (measured harmless).
// Exchange: {seq,value} u64 self-validating pairs, double-buffered by t&1.

typedef _Float16 f16;
typedef __attribute__((ext_vector_type(8)))  _Float16 f16x8;
typedef __attribute__((ext_vector_type(16))) float    f32x16;
typedef __attribute__((ext_vector_type(4)))  float    f32x4;
typedef __attribute__((ext_vector_type(4)))  float    float4v;
typedef unsigned long long u64;

#define OUT_STATES 33554432ull            // 32*1024*1024
#define EXCH_U64S  (16ull * 2 * 2 * 512)  // [bound][dir][slot][32*16]
#define EXCH_OFF   256                    // control region before exchange
#define WS_BYTES   (EXCH_OFF + EXCH_U64S * 8)

// dynamic LDS carve
#define AF_OFF  0         // f16 Afrag[35*64*8]            35840 B
#define HS_OFF  35840     // f16 Hs[32*136]                 8704 B
#define UP_OFF  44544     // float updS[32*308]            39424 B
#define DEC_OFF 83968     // float decL[304]                1216 B
#define EXL_OFF 85184     // float exL[512]                 2048 B
#define W1L_OFF 87232     // f16 W1L frags ks20..34        61440 B (LAST only)
#define LDS_TOT 148672

#define SPIN_CAP (1 << 21)   // hang-proof: give up after ~2M retries, latch

struct Ptrs {
  const float *x, *W1, *b1, *W2, *b2, *W1L, *b1L, *W2L, *b2L, *draw;
  float* out;
  int* ctl;            // ctl[0] = done flag for clock-keeper blocks
  u64* exch;
};

__device__ __forceinline__ float sigm(float v) { return 1.0f / (1.0f + __expf(-v)); }

// lgkm-only barrier: LDS producer/consumer sync without draining VMEM.
__device__ __forceinline__ void bar_lds() {
  asm volatile("s_waitcnt lgkmcnt(0)\n\ts_barrier" ::: "memory");
}

__device__ __forceinline__ u64* exslot(u64* e, int bound, int dir, int slot) {
  return e + (size_t)(((bound * 2 + dir) * 2 + slot) * 512);
}

// producer push: agent-scope relaxed store (R1/R4 semantics — measured correct)
__device__ __forceinline__ void push_ex(u64* p, unsigned seq, float val) {
  u64 v = ((u64)seq << 32) | (u64)__float_as_uint(val);
  __hip_atomic_store(p, v, __ATOMIC_RELAXED, __HIP_MEMORY_SCOPE_AGENT);
}

// batched system-scope polls: all loads issued in one asm, ONE vmcnt(0).
__device__ __forceinline__ void ld2_ag(const u64* pa, const u64* pb, u64& ga, u64& gb) {
  asm volatile("global_load_dwordx2 %0, %2, off sc0 sc1\n\t"
               "global_load_dwordx2 %1, %3, off sc0 sc1\n\t"
               "s_waitcnt vmcnt(0)"
               : "=&v"(ga), "=&v"(gb) : "v"(pa), "v"(pb) : "memory");
}

__device__ __forceinline__ void ld8_ag(const u64* a0, const u64* a1, const u64* a2, const u64* a3,
                                       const u64* a4, const u64* a5, const u64* a6, const u64* a7,
                                       u64& g0, u64& g1, u64& g2, u64& g3,
                                       u64& g4, u64& g5, u64& g6, u64& g7) {
  asm volatile("global_load_dwordx2 %0, %8, off sc0 sc1\n\t"
               "global_load_dwordx2 %1, %9, off sc0 sc1\n\t"
               "global_load_dwordx2 %2, %10, off sc0 sc1\n\t"
               "global_load_dwordx2 %3, %11, off sc0 sc1\n\t"
               "global_load_dwordx2 %4, %12, off sc0 sc1\n\t"
               "global_load_dwordx2 %5, %13, off sc0 sc1\n\t"
               "global_load_dwordx2 %6, %14, off sc0 sc1\n\t"
               "global_load_dwordx2 %7, %15, off sc0 sc1\n\t"
               "s_waitcnt vmcnt(0)"
               : "=&v"(g0), "=&v"(g1), "=&v"(g2), "=&v"(g3),
                 "=&v"(g4), "=&v"(g5), "=&v"(g6), "=&v"(g7)
               : "v"(a0), "v"(a1), "v"(a2), "v"(a3),
                 "v"(a4), "v"(a5), "v"(a6), "v"(a7)
               : "memory");
}

template<bool LAST>
__device__ void run_block(const int m, const Ptrs P) {
  constexpr int KS1 = LAST ? 35 : 20;   // stage1 K-steps of 16 (K = 560 / 320)
  constexpr int KSR = 20;               // K-steps held in registers (both)
  constexpr int U   = LAST ? 5  : 1;    // stage2 n-tiles per wave
  constexpr int NT  = LAST ? 19 : 4;    // stage2 total 16-wide n-tiles
  constexpr int SW  = LAST ? 304: 64;   // state slice width
  constexpr int NU  = LAST ? 38 : 8;    // update items per thread (32*SW/256)
  constexpr int UPW = LAST ? 308: 68;   // updS leading-dim pad

  const int tid = threadIdx.x;
  const int L = tid & 63;
  const int w = tid >> 6;               // wave id 0..3
  const int p0 = 48 * m;                // slice start (48*15 == 720)

  extern __shared__ __align__(16) char smem[];
  f16*   Afrag = (f16*)(smem + AF_OFF);
  f16*   Hs    = (f16*)(smem + HS_OFF);
  float* updS  = (float*)(smem + UP_OFF);
  float* decL  = (float*)(smem + DEC_OFF);
  float* exL   = (float*)(smem + EXL_OFF);
  f16*   W1Ll  = (f16*)(smem + W1L_OFF);

  int dead = 0;                          // sticky poll give-up latch

  // ---- load weights: ks<20 into registers; LAST ks20..34 into LDS frags ----
  f16x8 w1f[KSR];
  #pragma unroll
  for (int ks = 0; ks < KSR; ++ks) {
    #pragma unroll
    for (int e = 0; e < 8; ++e) {
      int c = 16 * ks + 8 * (L >> 5) + e;          // K index
      int h = 32 * w + (L & 31);                   // N index
      float wv = LAST ? P.W1L[(size_t)c * 128 + h]
                      : P.W1[((size_t)m * 320 + c) * 128 + h];
      w1f[ks][e] = (f16)wv;
    }
  }
  if (LAST) {
    for (int ks = 20; ks < 35; ++ks) {
      f16x8 bfrag;
      #pragma unroll
      for (int e = 0; e < 8; ++e) {
        int c = 16 * ks + 8 * (L >> 5) + e;
        int h = 32 * w + (L & 31);
        bfrag[e] = (f16)P.W1L[(size_t)c * 128 + h];
      }
      *(f16x8*)&W1Ll[((ks - 20) * 256 + tid) * 8] = bfrag;
    }
  }
  f16x8 w2f[U][4];
  float b2v[U];
  #pragma unroll
  for (int u = 0; u < U; ++u) {
    int nt = w + 4 * u;
    if (nt < NT) {
      int s = 16 * nt + (L & 15);
      #pragma unroll
      for (int ks = 0; ks < 4; ++ks)
        #pragma unroll
        for (int e = 0; e < 8; ++e) {
          int k = 32 * ks + 8 * ((L >> 4) & 3) + e;
          float wv = LAST ? P.W2L[(size_t)k * 304 + s]
                          : P.W2[((size_t)m * 128 + k) * 64 + s];
          w2f[u][ks][e] = (f16)wv;
        }
      b2v[u] = LAST ? P.b2L[s] : P.b2[m * 64 + s];
    }
  }
  const float b1v = LAST ? P.b1L[32 * w + (L & 31)] : P.b1[m * 128 + 32 * w + (L & 31)];

  for (int sl = tid; sl < SW; sl += 256) decL[sl] = sigm(P.draw[p0 + sl]);

  // zero A-frag (state cols must start at 0)
  for (int ch = tid; ch < 35 * 64; ch += 256) {
    f16x8 z;
    #pragma unroll
    for (int e = 0; e < 8; ++e) z[e] = (f16)0.0f;
    *(f16x8*)&Afrag[ch * 8] = z;
  }
  float sreg[NU];
  #pragma unroll
  for (int u = 0; u < NU; ++u) sreg[u] = 0.0f;

  // x staging identity; non-LAST keeps a persistent prefetch (xr), LAST
  // loads row t directly each step (register relief for m15).
  const int xb = tid >> 3, xc0 = (tid & 7) * 32;
  float4v xr[LAST ? 1 : 8];
  if (!LAST) {
    const float* xp = P.x + ((size_t)xb * 1024 + 0) * 256 + xc0;
    #pragma unroll
    for (int i = 0; i < 8; ++i) xr[i] = *(const float4v*)(xp + 4 * i);
  }
  __syncthreads();

  for (int t = 0; t < 1024; ++t) {
    const int slot = t & 1;
    const unsigned seq = (unsigned)(t + 1);

    // ---- stage x_t into A-frag chunks ----
    if (!LAST) {
      #pragma unroll
      for (int i = 0; i < 4; ++i) {
        int c = xc0 + 8 * i;
        int ks = c >> 4, h8 = (c >> 3) & 1;
        int chunk = (ks * 64 + xb + 32 * h8) ^ (ks & 7);
        f16x8 av;
        #pragma unroll
        for (int e = 0; e < 4; ++e) {
          av[e]     = (f16)xr[2 * i][e];
          av[4 + e] = (f16)xr[2 * i + 1][e];
        }
        *(f16x8*)&Afrag[chunk * 8] = av;
      }
    } else {
      const float* xp = P.x + ((size_t)xb * 1024 + t) * 256 + xc0;
      float4v xt[8];
      #pragma unroll
      for (int i = 0; i < 8; ++i) xt[i] = *(const float4v*)(xp + 4 * i);
      #pragma unroll
      for (int i = 0; i < 4; ++i) {
        int c = xc0 + 8 * i;
        int ks = c >> 4, h8 = (c >> 3) & 1;
        int chunk = (ks * 64 + xb + 32 * h8) ^ (ks & 7);
        f16x8 av;
        #pragma unroll
        for (int e = 0; e < 4; ++e) {
          av[e]     = (f16)xt[2 * i][e];
          av[4 + e] = (f16)xt[2 * i + 1][e];
        }
        *(f16x8*)&Afrag[chunk * 8] = av;
      }
    }
    bar_lds();

    // ---- stage1: H = silu(xl @ W1 + b1), wave w covers h in [32w, 32w+32) ----
    f32x16 acc;
    #pragma unroll
    for (int r = 0; r < 16; ++r) acc[r] = b1v;
    #pragma unroll
    for (int ks = 0; ks < KSR; ++ks) {
      int chunk = (ks * 64 + L) ^ (ks & 7);
      f16x8 a = *(const f16x8*)&Afrag[chunk * 8];
      acc = __builtin_amdgcn_mfma_f32_32x32x16_f16(a, w1f[ks], acc, 0, 0, 0);
    }
    if (LAST) {
      #pragma unroll
      for (int ks = 20; ks < 35; ++ks) {
        int chunk = (ks * 64 + L) ^ (ks & 7);
        f16x8 a = *(const f16x8*)&Afrag[chunk * 8];
        f16x8 b = *(const f16x8*)&W1Ll[((ks - 20) * 256 + tid) * 8];
        acc = __builtin_amdgcn_mfma_f32_32x32x16_f16(a, b, acc, 0, 0, 0);
      }
    }
    {
      int j = 32 * w + (L & 31);
      #pragma unroll
      for (int r = 0; r < 16; ++r) {
        int row = 4 * (L >> 5) + (r & 3) + 8 * (r >> 2);
        float v = acc[r];
        Hs[row * 136 + j] = (f16)(v * sigm(v));
      }
    }
    bar_lds();

    // ---- stage2: upd = H @ W2 + b2 (per-u accumulation: low reg pressure) ----
    #pragma unroll
    for (int u = 0; u < U; ++u) {
      int nt = w + 4 * u;
      if (nt < NT) {
        f32x4 acc2[2];
        #pragma unroll
        for (int mt = 0; mt < 2; ++mt)
          #pragma unroll
          for (int r = 0; r < 4; ++r) acc2[mt][r] = b2v[u];
        #pragma unroll
        for (int mt = 0; mt < 2; ++mt) {
          #pragma unroll
          for (int ks = 0; ks < 4; ++ks) {
            int hb = (L & 15) + 16 * mt;
            int kb = 32 * ks + 8 * ((L >> 4) & 3);
            f16x8 a = *(const f16x8*)&Hs[hb * 136 + kb];
            acc2[mt] = __builtin_amdgcn_mfma_f32_16x16x32_f16(a, w2f[u][ks], acc2[mt], 0, 0, 0);
          }
        }
        int s = 16 * nt + (L & 15);
        #pragma unroll
        for (int mt = 0; mt < 2; ++mt)
          #pragma unroll
          for (int r = 0; r < 4; ++r) {
            int b = 16 * mt + 4 * (L >> 4) + r;
            updS[b * UPW + s] = acc2[mt][r];
          }
        if (u == 0) {   // overlap strips live in tile nt==w
          if (!LAST) {
            if (w == 0 && m > 0) {          // left strip -> boundary m-1, dir1
              u64* base = exslot(P.exch, m - 1, 1, slot) + (L & 15);
              #pragma unroll
              for (int mt = 0; mt < 2; ++mt)
                #pragma unroll
                for (int r = 0; r < 4; ++r) {
                  int b = 16 * mt + 4 * (L >> 4) + r;
                  push_ex(base + b * 16, seq, acc2[mt][r]);
                }
            }
            if (w == 3) {                   // right strip -> boundary m, dir0
              u64* base = exslot(P.exch, m, 0, slot) + (L & 15);
              #pragma unroll
              for (int mt = 0; mt < 2; ++mt)
                #pragma unroll
                for (int r = 0; r < 4; ++r) {
                  int b = 16 * mt + 4 * (L >> 4) + r;
                  push_ex(base + b * 16, seq, acc2[mt][r]);
                }
            }
          } else {
            if (w == 0) {                   // left strip -> boundary 14, dir1
              u64* base = exslot(P.exch, 14, 1, slot) + (L & 15);
              #pragma unroll
              for (int mt = 0; mt < 2; ++mt)
                #pragma unroll
                for (int r = 0; r < 4; ++r) {
                  int b = 16 * mt + 4 * (L >> 4) + r;
                  push_ex(base + b * 16, seq, acc2[mt][r]);
                }
            }
          }
        }
      }
    }

    // prefetch next x (non-LAST; flies across the lgkm barrier)
    if (!LAST) {
      int tn = (t + 1 < 1024) ? (t + 1) : 1023;
      const float* xp = P.x + ((size_t)xb * 1024 + tn) * 256 + xc0;
      #pragma unroll
      for (int i = 0; i < 8; ++i) xr[i] = *(const float4v*)(xp + 4 * i);
    }
    bar_lds();

    // ---- state update: own (LDS) + neighbor (batched poll), EMA ----
    if (!LAST) {
      const int sl = tid & 63;
      const int b0 = tid >> 6;
      u64 got[8];
      const int side = (sl < 16 && m > 0) ? 0 : (sl >= 48 ? 1 : -1);
      if (side >= 0) {
        u64* base = (side == 0)
            ? (exslot(P.exch, m - 1, 0, slot) + sl)          // neighbor m-1's right strip
            : (exslot(P.exch, m, 1, slot) + (sl - 48));      // neighbor m+1's left strip
        const u64* a0 = base + (b0 + 0)  * 16;
        const u64* a1 = base + (b0 + 4)  * 16;
        const u64* a2 = base + (b0 + 8)  * 16;
        const u64* a3 = base + (b0 + 12) * 16;
        const u64* a4 = base + (b0 + 16) * 16;
        const u64* a5 = base + (b0 + 20) * 16;
        const u64* a6 = base + (b0 + 24) * 16;
        const u64* a7 = base + (b0 + 28) * 16;
        for (int spin = 0;; ++spin) {
          ld8_ag(a0, a1, a2, a3, a4, a5, a6, a7,
                 got[0], got[1], got[2], got[3], got[4], got[5], got[6], got[7]);
          bool ok = true;
          #pragma unroll
          for (int u = 0; u < 8; ++u)
            ok = ok && ((unsigned)(got[u] >> 32) == seq);
          if (ok) break;
          if (dead | (spin > SPIN_CAP)) { dead = 1; break; }   // hang-proof latch
          asm volatile("s_sleep 2");
        }
      }
      #pragma unroll
      for (int u = 0; u < 8; ++u) {
        int b = b0 + 4 * u;
        float val = updS[b * UPW + sl];
        if (side >= 0)
          val = (val + __uint_as_float((unsigned)(got[u] & 0xffffffffull))) * 0.5f;
        float d = decL[sl];
        float sn = d * sreg[u] + (1.0f - d) * val;
        sreg[u] = sn;
        int c = 256 + sl;
        int ks = c >> 4, h8 = (c >> 3) & 1, e = c & 7;
        int chunk = (ks * 64 + b + 32 * h8) ^ (ks & 7);
        Afrag[chunk * 8 + e] = (f16)sn;
        if (sl < 48) {
          P.out[(size_t)b * 1048576 + (size_t)t * 1024 + p0 + sl] = sn;
          if (t == 1023)
            P.out[OUT_STATES + (size_t)b * 1024 + p0 + sl] = sn;
        }
      }
    } else {
      // batched prepoll of m=14's right strip into LDS
      {
        u64* base = exslot(P.exch, 14, 0, slot);
        const u64* pa = base + tid;
        const u64* pb = base + tid + 256;
        u64 ga, gb;
        for (int spin = 0;; ++spin) {
          ld2_ag(pa, pb, ga, gb);
          if (((unsigned)(ga >> 32) == seq) && ((unsigned)(gb >> 32) == seq)) break;
          if (dead | (spin > SPIN_CAP)) { dead = 1; break; }   // hang-proof latch
          asm volatile("s_sleep 2");
        }
        exL[tid]       = __uint_as_float((unsigned)(ga & 0xffffffffull));
        exL[tid + 256] = __uint_as_float((unsigned)(gb & 0xffffffffull));
      }
      bar_lds();
      #pragma unroll
      for (int u = 0; u < NU; ++u) {
        const int q  = (256 * u) / 304;
        const int r2 = 256 * u - q * 304;
        int slx = tid + r2;
        int b  = q + (slx >= 304 ? 1 : 0);
        int sl = slx - (slx >= 304 ? 304 : 0);
        float val = updS[b * UPW + sl];
        if (sl < 16)
          val = (val + exL[b * 16 + sl]) * 0.5f;
        float d = decL[sl];
        float sn = d * sreg[u] + (1.0f - d) * val;
        sreg[u] = sn;
        int c = 256 + sl;
        int ks = c >> 4, h8 = (c >> 3) & 1, e = c & 7;
        int chunk = (ks * 64 + b + 32 * h8) ^ (ks & 7);
        Afrag[chunk * 8 + e] = (f16)sn;
        P.out[(size_t)b * 1048576 + (size_t)t * 1024 + 720 + sl] = sn;
        if (t == 1023)
          P.out[OUT_STATES + (size_t)b * 1024 + 720 + sl] = sn;
      }
    }
    // next x-stage writes disjoint Afrag chunks; loop-top bar_lds gates stage1
  }

  // signal clock-keepers to exit (m15 is the straggler)
  if (LAST && tid == 0)
    __hip_atomic_store(P.ctl, 1, __ATOMIC_RELAXED, __HIP_MEMORY_SCOPE_AGENT);
}

// Dependent-MFMA spin keeper (R4, measured active: MfmaUtil 13.9%).
__device__ void clock_keeper(const Ptrs P) {
  f16x8 z;
  #pragma unroll
  for (int e = 0; e < 8; ++e) z[e] = (f16)((threadIdx.x & 1) ? 0.0f : 1e-6f);
  f32x4 acc = {0.0f, 0.0f, 0.0f, 0.0f};
  for (;;) {
    #pragma unroll 16
    for (int i = 0; i < 1024; ++i)
      acc = __builtin_amdgcn_mfma_f32_16x16x32_f16(z, z, acc, 0, 0, 0);
    if (__hip_atomic_load(P.ctl, __ATOMIC_RELAXED, __HIP_MEMORY_SCOPE_AGENT) != 0)
      break;
  }
  if (acc[0] == 123.456f)
    ((volatile float*)P.out)[0] = acc[0];
}

__global__ __launch_bounds__(256, 1) void ssm_kernel(Ptrs P) {
  const int blk = blockIdx.x;
  if (blk >= 16) { clock_keeper(P); return; }
  if (blk == 15) run_block<true>(15, P);
  else           run_block<false>(blk, P);
}

extern "C" void kernel_launch(void* const* d_in, const int* in_sizes, int n_in,
                              void* d_out, int out_size, void* d_ws, size_t ws_size,
                              hipStream_t stream) {
  (void)in_sizes; (void)n_in; (void)out_size; (void)ws_size;
  Ptrs P;
  P.x    = (const float*)d_in[0];
  P.W1   = (const float*)d_in[1];
  P.b1   = (const float*)d_in[2];
  P.W2   = (const float*)d_in[3];
  P.b2   = (const float*)d_in[4];
  P.W1L  = (const float*)d_in[5];
  P.b1L  = (const float*)d_in[6];
  P.W2L  = (const float*)d_in[7];
  P.b2L  = (const float*)d_in[8];
  P.draw = (const float*)d_in[9];
  P.out  = (float*)d_out;
  P.ctl  = (int*)d_ws;
  P.exch = (u64*)((char*)d_ws + EXCH_OFF);

  hipMemsetAsync(d_ws, 0, WS_BYTES, stream);
  hipLaunchKernelGGL(ssm_kernel, dim3(256), dim3(256), LDS_TOT, stream, P);
}